// Round 1
// baseline (855.738 us; speedup 1.0000x reference)
//
#include <hip/hip_runtime.h>
#include <hip/hip_bf16.h>

#define B_SZ 8192
#define D_SZ 4096   // K
#define H_SZ 2048
#define N4H  8192   // 4*H = N

typedef __attribute__((ext_vector_type(8))) __bf16 bf16x8;
typedef __attribute__((ext_vector_type(4))) float f32x4;

#define GPTR(p) ((__attribute__((address_space(1))) void*)(p))
#define LPTR(p) ((__attribute__((address_space(3))) void*)(p))

// ---------------------------------------------------------------------------
// 1) combine = bf16(input + hidden), vectorized
// ---------------------------------------------------------------------------
__global__ void combine_k(const float* __restrict__ x, const float* __restrict__ h,
                          __hip_bfloat16* __restrict__ c) {
    const size_t n4 = (size_t)B_SZ * D_SZ / 4;
    const size_t stride = (size_t)gridDim.x * blockDim.x;
    for (size_t i = (size_t)blockIdx.x * blockDim.x + threadIdx.x; i < n4; i += stride) {
        float4 a = ((const float4*)x)[i];
        float4 b = ((const float4*)h)[i];
        short4 r;
        r.x = __builtin_bit_cast(short, __float2bfloat16(a.x + b.x));
        r.y = __builtin_bit_cast(short, __float2bfloat16(a.y + b.y));
        r.z = __builtin_bit_cast(short, __float2bfloat16(a.z + b.z));
        r.w = __builtin_bit_cast(short, __float2bfloat16(a.w + b.w));
        ((short4*)c)[i] = r;
    }
}

// ---------------------------------------------------------------------------
// 2) WT[n][k] = bf16(W_g[k][n&2047]),  n in [0,8192), g = n>>11
//    32x32 tiled transpose, block (32,8)
// ---------------------------------------------------------------------------
__global__ void transpose_w_k(const float* __restrict__ Wf, const float* __restrict__ Wc,
                              const float* __restrict__ Wi, const float* __restrict__ Wo,
                              __hip_bfloat16* __restrict__ WT) {
    __shared__ float t[32][33];
    const int k0 = blockIdx.x * 32;
    const int n0 = blockIdx.y * 32;
    const float* W = (n0 < H_SZ) ? Wf : (n0 < 2 * H_SZ) ? Wc : (n0 < 3 * H_SZ) ? Wi : Wo;
    const int nc = n0 & (H_SZ - 1);
    const int tx = threadIdx.x, ty = threadIdx.y;
#pragma unroll
    for (int j = 0; j < 4; ++j)
        t[ty + j * 8][tx] = W[(size_t)(k0 + ty + j * 8) * H_SZ + nc + tx];
    __syncthreads();
#pragma unroll
    for (int j = 0; j < 4; ++j)
        WT[(size_t)(n0 + ty + j * 8) * D_SZ + k0 + tx] = __float2bfloat16(t[tx][ty + j * 8]);
}

// ---------------------------------------------------------------------------
// 3) GEMM: C[8192][8192] bf16 = A[8192][4096] x WT^T  (m97 structure)
//    128x128 tile, BK=32, 4 waves (2x2), global_load_lds width-16 staging
// ---------------------------------------------------------------------------
__global__ __launch_bounds__(256) void gemm_bt_k(
    const __hip_bfloat16* __restrict__ A,   // [8192][4096] row-major
    const __hip_bfloat16* __restrict__ BT,  // [8192][4096] row-major (N-major)
    __hip_bfloat16* __restrict__ C)         // [8192][8192]
{
    __shared__ __hip_bfloat16 As[128 * 32];
    __shared__ __hip_bfloat16 Bs[128 * 32];

    const int tid  = threadIdx.x;
    const int wave = tid >> 6;
    const int lane = tid & 63;
    const int m0 = blockIdx.y * 128;
    const int n0 = blockIdx.x * 128;

    const int wr = wave >> 1, wc = wave & 1;  // wave -> 64x64 sub-tile
    const int fr = lane & 15;                 // fragment row/col
    const int ko = (lane >> 4) * 8;           // k-offset within BK=32

    const int srow = lane >> 2;               // staging row within 16-row chunk
    const int scol = (lane & 3) * 8;          // staging col (8 bf16 = 16B)

    f32x4 acc[4][4] = {};

    for (int k0 = 0; k0 < D_SZ; k0 += 32) {
        // ---- stage A/B tiles: 2 x global_load_lds_dwordx4 per wave per tile
#pragma unroll
        for (int i = 0; i < 2; ++i) {
            const int chunk = wave * 2 + i;   // 0..7, 16 rows each
            const int r = chunk * 16 + srow;
            __builtin_amdgcn_global_load_lds(
                GPTR(A + (size_t)(m0 + r) * D_SZ + k0 + scol),
                LPTR(As + chunk * 512), 16, 0, 0);
            __builtin_amdgcn_global_load_lds(
                GPTR(BT + (size_t)(n0 + r) * D_SZ + k0 + scol),
                LPTR(Bs + chunk * 512), 16, 0, 0);
        }
        __syncthreads();  // drains vmcnt before use

        bf16x8 af[4], bfr[4];
#pragma unroll
        for (int mi = 0; mi < 4; ++mi)
            af[mi] = *(const bf16x8*)(As + (wr * 64 + mi * 16 + fr) * 32 + ko);
#pragma unroll
        for (int ni = 0; ni < 4; ++ni)
            bfr[ni] = *(const bf16x8*)(Bs + (wc * 64 + ni * 16 + fr) * 32 + ko);

#pragma unroll
        for (int mi = 0; mi < 4; ++mi)
#pragma unroll
            for (int ni = 0; ni < 4; ++ni)
                acc[mi][ni] = __builtin_amdgcn_mfma_f32_16x16x32_bf16(
                    af[mi], bfr[ni], acc[mi][ni], 0, 0, 0);

        __syncthreads();  // before next staging overwrites LDS
    }

    // ---- epilogue: C/D layout col=lane&15, row=(lane>>4)*4+j  (m89-verified)
    const int crow = (lane >> 4) * 4;
    const int ccol = lane & 15;
#pragma unroll
    for (int mi = 0; mi < 4; ++mi)
#pragma unroll
        for (int ni = 0; ni < 4; ++ni) {
            const size_t base_r = (size_t)(m0 + wr * 64 + mi * 16 + crow);
            const size_t cidx = (size_t)(n0 + wc * 64 + ni * 16 + ccol);
#pragma unroll
            for (int j = 0; j < 4; ++j)
                C[(base_r + j) * (size_t)N4H + cidx] = __float2bfloat16(acc[mi][ni][j]);
        }
}

// ---------------------------------------------------------------------------
// 4) gate math epilogue: bias + activations -> out, hidden_state, cell_state
// ---------------------------------------------------------------------------
__device__ __forceinline__ float bfbits(unsigned v, int j) {
    return __uint_as_float(j ? (v & 0xffff0000u) : (v << 16));
}
__device__ __forceinline__ float fsig(float x) { return 1.f / (1.f + __expf(-x)); }
__device__ __forceinline__ float ftanh(float x) {
    x = fminf(fmaxf(x, -15.f), 15.f);
    float e = __expf(2.f * x);
    return (e - 1.f) / (e + 1.f);
}

__global__ void gates_k(const __hip_bfloat16* __restrict__ g, const float* __restrict__ cell,
                        const float* __restrict__ bfb, const float* __restrict__ bcb,
                        const float* __restrict__ bib, const float* __restrict__ bob,
                        float* __restrict__ out) {
    const size_t BH = (size_t)B_SZ * H_SZ;
    float* hid = out + BH;
    float* cst = out + 2 * BH;
    const size_t n2 = BH / 2;
    const size_t stride = (size_t)gridDim.x * blockDim.x;
    for (size_t i = (size_t)blockIdx.x * blockDim.x + threadIdx.x; i < n2; i += stride) {
        const size_t e = i * 2;                 // element pair start
        const int b = (int)(e >> 11);           // H = 2048
        const int n = (int)(e & 2047);          // even
        const unsigned* row = (const unsigned*)(g + (size_t)b * N4H);
        const unsigned vf = row[(n) >> 1];
        const unsigned vc = row[(n + 2048) >> 1];
        const unsigned vi = row[(n + 4096) >> 1];
        const unsigned vo = row[(n + 6144) >> 1];
        const float2 cl = *(const float2*)(cell + e);
        const float2 b_f = *(const float2*)(bfb + n);
        const float2 b_c = *(const float2*)(bcb + n);
        const float2 b_i = *(const float2*)(bib + n);
        const float2 b_o = *(const float2*)(bob + n);
        float r_out[2], r_hid[2], r_cst[2];
#pragma unroll
        for (int j = 0; j < 2; ++j) {
            const float gf = bfbits(vf, j) + (j ? b_f.y : b_f.x);
            const float gc = bfbits(vc, j) + (j ? b_c.y : b_c.x);
            const float gi = bfbits(vi, j) + (j ? b_i.y : b_i.x);
            const float go = bfbits(vo, j) + (j ? b_o.y : b_o.x);
            const float ft = fsig(gf);
            const float ct = ftanh(gc);
            const float it = fsig(fsig(gi));   // double sigmoid, faithful
            const float ot = fsig(go);
            const float cv = (j ? cl.y : cl.x);
            const float cs = cv * ft + ct * it;
            r_out[j] = ot;
            r_cst[j] = cs;
            r_hid[j] = ot * ftanh(cs);
        }
        *(float2*)(out + e) = make_float2(r_out[0], r_out[1]);
        *(float2*)(hid + e) = make_float2(r_hid[0], r_hid[1]);
        *(float2*)(cst + e) = make_float2(r_cst[0], r_cst[1]);
    }
}

// ---------------------------------------------------------------------------
extern "C" void kernel_launch(void* const* d_in, const int* in_sizes, int n_in,
                              void* d_out, int out_size, void* d_ws, size_t ws_size,
                              hipStream_t stream) {
    const float* input  = (const float*)d_in[0];
    const float* hidden = (const float*)d_in[1];
    const float* cell   = (const float*)d_in[2];
    const float* Wf     = (const float*)d_in[3];
    const float* bfb    = (const float*)d_in[4];
    const float* Wc     = (const float*)d_in[5];
    const float* bcb    = (const float*)d_in[6];
    const float* Wi     = (const float*)d_in[7];
    const float* bib    = (const float*)d_in[8];
    const float* Wo     = (const float*)d_in[9];
    const float* bob    = (const float*)d_in[10];
    float* out = (float*)d_out;

    char* ws = (char*)d_ws;
    __hip_bfloat16* comb  = (__hip_bfloat16*)ws;                                    // 64 MiB
    __hip_bfloat16* WT    = (__hip_bfloat16*)(ws + (size_t)B_SZ * D_SZ * 2);        // 64 MiB
    __hip_bfloat16* gates = (__hip_bfloat16*)(ws + (size_t)B_SZ * D_SZ * 2
                                                 + (size_t)N4H * D_SZ * 2);         // 128 MiB

    combine_k<<<2048, 256, 0, stream>>>(input, hidden, comb);
    transpose_w_k<<<dim3(D_SZ / 32, N4H / 32), dim3(32, 8), 0, stream>>>(Wf, Wc, Wi, Wo, WT);
    gemm_bt_k<<<dim3(N4H / 128, B_SZ / 128), 256, 0, stream>>>(comb, WT, gates);
    gates_k<<<2048, 256, 0, stream>>>(gates, cell, bfb, bcb, bib, bob, out);
}

// Round 2
// 674.753 us; speedup vs baseline: 1.2682x; 1.2682x over previous
//
#include <hip/hip_runtime.h>
#include <hip/hip_bf16.h>

#define B_SZ 8192
#define D_SZ 4096   // K
#define H_SZ 2048
#define N4H  8192   // 4*H = N
#define NT   (D_SZ / 64)   // 64 K-tiles of BK=64

typedef __attribute__((ext_vector_type(8))) __bf16 bf16x8;
typedef __attribute__((ext_vector_type(4))) float f32x4;

#define GPTR(p) ((__attribute__((address_space(1))) void*)(p))
#define LPTR(p) ((__attribute__((address_space(3))) void*)(p))

// ---------------------------------------------------------------------------
// 1) combine = bf16(input + hidden), vectorized
// ---------------------------------------------------------------------------
__global__ void combine_k(const float* __restrict__ x, const float* __restrict__ h,
                          __hip_bfloat16* __restrict__ c) {
    const size_t n4 = (size_t)B_SZ * D_SZ / 4;
    const size_t stride = (size_t)gridDim.x * blockDim.x;
    for (size_t i = (size_t)blockIdx.x * blockDim.x + threadIdx.x; i < n4; i += stride) {
        float4 a = ((const float4*)x)[i];
        float4 b = ((const float4*)h)[i];
        short4 r;
        r.x = __builtin_bit_cast(short, __float2bfloat16(a.x + b.x));
        r.y = __builtin_bit_cast(short, __float2bfloat16(a.y + b.y));
        r.z = __builtin_bit_cast(short, __float2bfloat16(a.z + b.z));
        r.w = __builtin_bit_cast(short, __float2bfloat16(a.w + b.w));
        ((short4*)c)[i] = r;
    }
}

// ---------------------------------------------------------------------------
// 2) WT[n][k] = bf16(W_g[k][n&2047]),  n in [0,8192), g = n>>11
// ---------------------------------------------------------------------------
__global__ void transpose_w_k(const float* __restrict__ Wf, const float* __restrict__ Wc,
                              const float* __restrict__ Wi, const float* __restrict__ Wo,
                              __hip_bfloat16* __restrict__ WT) {
    __shared__ float t[32][33];
    const int k0 = blockIdx.x * 32;
    const int n0 = blockIdx.y * 32;
    const float* W = (n0 < H_SZ) ? Wf : (n0 < 2 * H_SZ) ? Wc : (n0 < 3 * H_SZ) ? Wi : Wo;
    const int nc = n0 & (H_SZ - 1);
    const int tx = threadIdx.x, ty = threadIdx.y;
#pragma unroll
    for (int j = 0; j < 4; ++j)
        t[ty + j * 8][tx] = W[(size_t)(k0 + ty + j * 8) * H_SZ + nc + tx];
    __syncthreads();
#pragma unroll
    for (int j = 0; j < 4; ++j)
        WT[(size_t)(n0 + ty + j * 8) * D_SZ + k0 + tx] = __float2bfloat16(t[tx][ty + j * 8]);
}

// ---------------------------------------------------------------------------
// 3) GEMM: 256x256 tile, BK=64, 8 waves (2Mx4N), 8-phase schedule
//    (T1 XCD-swizzle + T2 XOR-swizzle + T3/T4 counted vmcnt + T5 setprio)
//
//    LDS 128 KiB: [buf0 A 32K][buf0 B 32K][buf1 A 32K][buf1 B 32K]
//    A region rows (lds): qm*128 + wr*64 + (mi*16+fr)  <->  tile row wr*128+qm*64+...
//    B region rows (lds): qn*128 + wc*32 + (nf*16+fr)  <->  tile N   wc*64+qn*32+...
//    Swizzle: 16B slot ^= (lds_row & 7), applied on global SOURCE addr (write side,
//    global_load_lds dest is linear) and on ds_read addr (read side) — involution.
//
//    Stage stream per tile: [A0, B0, A1, B1]; prologue = t0 all + t1 A0,B0,A1.
//    Group G_t (4 phases): ph1 stages B1(t+1)->oth, ph2/3/4 stage A0/B0/A1(t+2)->cur.
//    Region safety: each stage's target region had its last ds_read one phase
//    earlier, drained by that phase's lgkmcnt(0)+barrier#2 before the stage issues.
//    vmcnt(6) (=3 half-tiles in flight) inside ph4 BEFORE the final barrier, so all
//    waves' tile-(t+1) loads are landed before any wave reads them in the next group.
// ---------------------------------------------------------------------------

#define BAR()                                    \
    do {                                         \
        asm volatile("" ::: "memory");           \
        __builtin_amdgcn_s_barrier();            \
        asm volatile("" ::: "memory");           \
    } while (0)

#define STAGE(pbase, HSTRIDE, h, kt, region)                                           \
    do {                                                                               \
        __builtin_amdgcn_global_load_lds(                                              \
            GPTR((pbase) + (size_t)((h) * (HSTRIDE)) * D_SZ + (size_t)(kt) * 64),      \
            LPTR(smem + (region) + (h) * 16384 + wave * 1024), 16, 0, 0);              \
        __builtin_amdgcn_global_load_lds(                                              \
            GPTR((pbase) + (size_t)(128 + (h) * (HSTRIDE)) * D_SZ + (size_t)(kt) * 64),\
            LPTR(smem + (region) + (h) * 16384 + 8192 + wave * 1024), 16, 0, 0);       \
    } while (0)

#define LDA(dst, base, qm)                                                             \
    do {                                                                               \
        _Pragma("unroll") for (int mi = 0; mi < 4; ++mi) {                             \
            const int row_ = (qm) * 128 + wr * 64 + mi * 16 + fr;                      \
            dst[mi][0] = *(const bf16x8*)(smem + (base) + row_ * 128 + sw0);           \
            dst[mi][1] = *(const bf16x8*)(smem + (base) + row_ * 128 + sw1);           \
        }                                                                              \
    } while (0)

#define LDB(dst, base, qn)                                                             \
    do {                                                                               \
        _Pragma("unroll") for (int nf = 0; nf < 2; ++nf) {                             \
            const int row_ = (qn) * 128 + wc * 32 + nf * 16 + fr;                      \
            dst[nf][0] = *(const bf16x8*)(smem + (base) + row_ * 128 + sw0);           \
            dst[nf][1] = *(const bf16x8*)(smem + (base) + row_ * 128 + sw1);           \
        }                                                                              \
    } while (0)

#define MFMA_Q(qm, qn, areg, breg)                                                     \
    do {                                                                               \
        _Pragma("unroll") for (int mi = 0; mi < 4; ++mi)                               \
        _Pragma("unroll") for (int nf = 0; nf < 2; ++nf)                               \
        _Pragma("unroll") for (int ks = 0; ks < 2; ++ks)                               \
            acc[(qm) * 4 + mi][(qn) * 2 + nf] =                                        \
                __builtin_amdgcn_mfma_f32_16x16x32_bf16(                               \
                    areg[mi][ks], breg[nf][ks],                                        \
                    acc[(qm) * 4 + mi][(qn) * 2 + nf], 0, 0, 0);                       \
    } while (0)

__global__ __launch_bounds__(512, 2) void gemm8_k(
    const __hip_bfloat16* __restrict__ A,   // [8192][4096] row-major (M-major)
    const __hip_bfloat16* __restrict__ BT,  // [8192][4096] row-major (N-major)
    __hip_bfloat16* __restrict__ C)         // [8192][8192]
{
    extern __shared__ char smem[];

    const int tid  = threadIdx.x;
    const int wave = tid >> 6;
    const int lane = tid & 63;
    const int wr = wave >> 2;   // 0..1  (wave rows: wr*128)
    const int wc = wave & 3;    // 0..3  (wave cols: wc*64)
    const int fr = lane & 15;
    const int sw0 = (((lane >> 4) + 0) ^ (fr & 7)) << 4;   // ks=0 swizzled 16B slot
    const int sw1 = (((lane >> 4) + 4) ^ (fr & 7)) << 4;   // ks=1

    // XCD-aware swizzle (bijective: 1024 % 8 == 0)
    const int wg = (blockIdx.x & 7) * 128 + (blockIdx.x >> 3);
    const int n0 = (wg & 31) * 256;
    const int m0 = (wg >> 5) * 256;

    // per-thread staging source (pre-swizzled global column)
    const int r0   = tid >> 3;                               // 0..63 (lds half-row, i=0)
    const int col0 = ((tid & 7) ^ (r0 & 7)) << 3;            // swizzled element col
    const __hip_bfloat16* pA = A  + (size_t)(m0 + r0) * D_SZ + col0;
    const __hip_bfloat16* pB = BT + (size_t)(n0 + ((r0 >> 5) << 6) + (r0 & 31)) * D_SZ + col0;

    f32x4 acc[8][4] = {};
    bf16x8 a[4][2], b0[2][2], b1[2][2];

    // ---- prologue: tile0 (A0,B0,A1,B1) -> buf0, tile1 (A0,B0,A1) -> buf1
    STAGE(pA, 64, 0, 0, 0);
    STAGE(pB, 32, 0, 0, 32768);
    STAGE(pA, 64, 1, 0, 0);
    STAGE(pB, 32, 1, 0, 32768);
    STAGE(pA, 64, 0, 1, 65536);
    STAGE(pB, 32, 0, 1, 98304);
    STAGE(pA, 64, 1, 1, 65536);
    asm volatile("s_waitcnt vmcnt(6)" ::: "memory");   // tile0 fully landed
    BAR();

    for (int t = 0; t < NT; ++t) {
        const int curA = (t & 1) * 65536;
        const int curB = curA + 32768;
        const int othB = (curA ^ 65536) + 32768;

        // ---- phase 1: q(0,0)  [12 ds_reads]
        LDA(a, curA, 0);
        LDB(b0, curB, 0);
        if (t + 1 < NT) STAGE(pB, 32, 1, t + 1, othB);   // B1(t+1) -> other buf
        BAR();
        asm volatile("s_waitcnt lgkmcnt(0)" ::: "memory");
        __builtin_amdgcn_s_setprio(1);
        MFMA_Q(0, 0, a, b0);
        __builtin_amdgcn_s_setprio(0);
        BAR();

        // ---- phase 2: q(0,1)  [4 ds_reads; A qm=0 reused]
        LDB(b1, curB, 1);
        if (t + 2 < NT) STAGE(pA, 64, 0, t + 2, curA);   // A0 region free after ph1
        BAR();
        asm volatile("s_waitcnt lgkmcnt(0)" ::: "memory");
        __builtin_amdgcn_s_setprio(1);
        MFMA_Q(0, 1, a, b1);
        __builtin_amdgcn_s_setprio(0);
        BAR();

        // ---- phase 3: q(1,0)  [8 ds_reads; B qn=0 reused from regs]
        LDA(a, curA, 1);
        if (t + 2 < NT) STAGE(pB, 32, 0, t + 2, curB);   // B0 region free after ph1
        BAR();
        asm volatile("s_waitcnt lgkmcnt(0)" ::: "memory");
        __builtin_amdgcn_s_setprio(1);
        MFMA_Q(1, 0, a, b0);
        __builtin_amdgcn_s_setprio(0);
        BAR();

        // ---- phase 4: q(1,1)  [0 ds_reads; all operands in regs]
        if (t + 2 < NT) STAGE(pA, 64, 1, t + 2, curA);   // A1 region free after ph3
        BAR();
        __builtin_amdgcn_s_setprio(1);
        MFMA_Q(1, 1, a, b1);
        __builtin_amdgcn_s_setprio(0);
        // counted drain BEFORE barrier: all waves' tile-(t+1) halves landed after this
        if (t + 2 < NT) {
            asm volatile("s_waitcnt vmcnt(6)" ::: "memory");
        } else if (t + 1 < NT) {
            asm volatile("s_waitcnt vmcnt(0)" ::: "memory");
        }
        BAR();
    }

    // ---- epilogue: C/D layout col=lane&15, row=(lane>>4)*4+j
    const int crow = (lane >> 4) * 4;
    const int ccol = lane & 15;
#pragma unroll
    for (int ai = 0; ai < 8; ++ai)
#pragma unroll
        for (int bj = 0; bj < 4; ++bj) {
            const size_t base_r = (size_t)(m0 + wr * 128 + ai * 16 + crow);
            const size_t cidx   = (size_t)(n0 + wc * 64 + bj * 16 + ccol);
#pragma unroll
            for (int j = 0; j < 4; ++j)
                C[(base_r + j) * (size_t)N4H + cidx] = __float2bfloat16(acc[ai][bj][j]);
        }
}

// ---------------------------------------------------------------------------
// 4) gate math epilogue: bias + activations -> out, hidden_state, cell_state
// ---------------------------------------------------------------------------
__device__ __forceinline__ float bfbits(unsigned v, int j) {
    return __uint_as_float(j ? (v & 0xffff0000u) : (v << 16));
}
__device__ __forceinline__ float fsig(float x) { return 1.f / (1.f + __expf(-x)); }
__device__ __forceinline__ float ftanh(float x) {
    x = fminf(fmaxf(x, -15.f), 15.f);
    float e = __expf(2.f * x);
    return (e - 1.f) / (e + 1.f);
}

__global__ void gates_k(const __hip_bfloat16* __restrict__ g, const float* __restrict__ cell,
                        const float* __restrict__ bfb, const float* __restrict__ bcb,
                        const float* __restrict__ bib, const float* __restrict__ bob,
                        float* __restrict__ out) {
    const size_t BH = (size_t)B_SZ * H_SZ;
    float* hid = out + BH;
    float* cst = out + 2 * BH;
    const size_t n2 = BH / 2;
    const size_t stride = (size_t)gridDim.x * blockDim.x;
    for (size_t i = (size_t)blockIdx.x * blockDim.x + threadIdx.x; i < n2; i += stride) {
        const size_t e = i * 2;
        const int b = (int)(e >> 11);
        const int n = (int)(e & 2047);
        const unsigned* row = (const unsigned*)(g + (size_t)b * N4H);
        const unsigned vf = row[(n) >> 1];
        const unsigned vc = row[(n + 2048) >> 1];
        const unsigned vi = row[(n + 4096) >> 1];
        const unsigned vo = row[(n + 6144) >> 1];
        const float2 cl = *(const float2*)(cell + e);
        const float2 b_f = *(const float2*)(bfb + n);
        const float2 b_c = *(const float2*)(bcb + n);
        const float2 b_i = *(const float2*)(bib + n);
        const float2 b_o = *(const float2*)(bob + n);
        float r_out[2], r_hid[2], r_cst[2];
#pragma unroll
        for (int j = 0; j < 2; ++j) {
            const float gf = bfbits(vf, j) + (j ? b_f.y : b_f.x);
            const float gc = bfbits(vc, j) + (j ? b_c.y : b_c.x);
            const float gi = bfbits(vi, j) + (j ? b_i.y : b_i.x);
            const float go = bfbits(vo, j) + (j ? b_o.y : b_o.x);
            const float ft = fsig(gf);
            const float ct = ftanh(gc);
            const float it = fsig(fsig(gi));   // double sigmoid, faithful
            const float ot = fsig(go);
            const float cv = (j ? cl.y : cl.x);
            const float cs = cv * ft + ct * it;
            r_out[j] = ot;
            r_cst[j] = cs;
            r_hid[j] = ot * ftanh(cs);
        }
        *(float2*)(out + e) = make_float2(r_out[0], r_out[1]);
        *(float2*)(hid + e) = make_float2(r_hid[0], r_hid[1]);
        *(float2*)(cst + e) = make_float2(r_cst[0], r_cst[1]);
    }
}

// ---------------------------------------------------------------------------
extern "C" void kernel_launch(void* const* d_in, const int* in_sizes, int n_in,
                              void* d_out, int out_size, void* d_ws, size_t ws_size,
                              hipStream_t stream) {
    const float* input  = (const float*)d_in[0];
    const float* hidden = (const float*)d_in[1];
    const float* cell   = (const float*)d_in[2];
    const float* Wf     = (const float*)d_in[3];
    const float* bfb    = (const float*)d_in[4];
    const float* Wc     = (const float*)d_in[5];
    const float* bcb    = (const float*)d_in[6];
    const float* Wi     = (const float*)d_in[7];
    const float* bib    = (const float*)d_in[8];
    const float* Wo     = (const float*)d_in[9];
    const float* bob    = (const float*)d_in[10];
    float* out = (float*)d_out;

    char* ws = (char*)d_ws;
    __hip_bfloat16* comb  = (__hip_bfloat16*)ws;                                    // 64 MiB
    __hip_bfloat16* WT    = (__hip_bfloat16*)(ws + (size_t)B_SZ * D_SZ * 2);        // 64 MiB
    __hip_bfloat16* gates = (__hip_bfloat16*)(ws + (size_t)B_SZ * D_SZ * 2
                                                 + (size_t)N4H * D_SZ * 2);         // 128 MiB

    hipFuncSetAttribute(reinterpret_cast<const void*>(gemm8_k),
                        hipFuncAttributeMaxDynamicSharedMemorySize, 131072);

    combine_k<<<2048, 256, 0, stream>>>(input, hidden, comb);
    transpose_w_k<<<dim3(D_SZ / 32, N4H / 32), dim3(32, 8), 0, stream>>>(Wf, Wc, Wi, Wo, WT);
    gemm8_k<<<1024, 512, 131072, stream>>>(comb, WT, gates);
    gates_k<<<2048, 256, 0, stream>>>(gates, cell, bfb, bcb, bib, bob, out);
}

// Round 3
// 630.640 us; speedup vs baseline: 1.3569x; 1.0700x over previous
//
#include <hip/hip_runtime.h>
#include <hip/hip_bf16.h>

#define B_SZ 8192
#define D_SZ 4096   // K
#define H_SZ 2048
#define N4H  8192   // 4*H = N (gate-interleaved n' space)
#define NT   (D_SZ / 64)   // 64 K-tiles of BK=64

typedef __attribute__((ext_vector_type(8))) __bf16 bf16x8;
typedef __attribute__((ext_vector_type(4))) float f32x4;

#define GPTR(p) ((__attribute__((address_space(1))) void*)(p))
#define LPTR(p) ((__attribute__((address_space(3))) void*)(p))

// ---------------------------------------------------------------------------
// 1) prep: [blocks 0..2047]    combine = bf16(input + hidden)
//    [blocks 2048..34815]      WT[n'][k] = bf16(W_g[k][h]),
//                              n' = (h>>4)*64 + g*16 + (h&15)   (gate-interleave)
// ---------------------------------------------------------------------------
__global__ void prep_k(const float* __restrict__ x, const float* __restrict__ h,
                       __hip_bfloat16* __restrict__ comb,
                       const float* __restrict__ Wf, const float* __restrict__ Wc,
                       const float* __restrict__ Wi, const float* __restrict__ Wo,
                       __hip_bfloat16* __restrict__ WT) {
    __shared__ float t[32][33];
    if (blockIdx.x < 2048) {
        const size_t n4 = (size_t)B_SZ * D_SZ / 4;
        const size_t stride = (size_t)2048 * 256;
        for (size_t i = (size_t)blockIdx.x * 256 + threadIdx.x; i < n4; i += stride) {
            f32x4 a = __builtin_nontemporal_load((const f32x4*)x + i);
            f32x4 b = __builtin_nontemporal_load((const f32x4*)h + i);
            short4 r;
            r.x = __builtin_bit_cast(short, __float2bfloat16(a.x + b.x));
            r.y = __builtin_bit_cast(short, __float2bfloat16(a.y + b.y));
            r.z = __builtin_bit_cast(short, __float2bfloat16(a.z + b.z));
            r.w = __builtin_bit_cast(short, __float2bfloat16(a.w + b.w));
            ((short4*)comb)[i] = r;
        }
    } else {
        const int b = blockIdx.x - 2048;      // 0..32767
        const int k0 = (b & 127) * 32;        // K block
        const int n0 = (b >> 7) * 32;         // old-layout n block (g*2048 + h)
        const float* W = (n0 < H_SZ) ? Wf : (n0 < 2 * H_SZ) ? Wc
                       : (n0 < 3 * H_SZ) ? Wi : Wo;
        const int g = n0 >> 11;
        const int nc = n0 & (H_SZ - 1);
        const int tx = threadIdx.x & 31, ty = threadIdx.x >> 5;
#pragma unroll
        for (int j = 0; j < 4; ++j)
            t[ty + j * 8][tx] = __builtin_nontemporal_load(
                W + (size_t)(k0 + ty + j * 8) * H_SZ + nc + tx);
        __syncthreads();
#pragma unroll
        for (int j = 0; j < 4; ++j) {
            const int h2 = nc + ty + j * 8;                       // h index
            const int np = ((h2 >> 4) << 6) + (g << 4) + (h2 & 15);
            WT[(size_t)np * D_SZ + k0 + tx] = __float2bfloat16(t[tx][ty + j * 8]);
        }
    }
}

// ---------------------------------------------------------------------------
// 2) GEMM + fused LSTM epilogue: 256x256 tile, BK=64, 8 waves (2Mx4N),
//    8-phase schedule (T1+T2+T3/T4+T5), manual x2 K-unroll (static LDS bases).
//    Phase/sync structure identical to round-2 (verified).
// ---------------------------------------------------------------------------

#define BAR()                                    \
    do {                                         \
        asm volatile("" ::: "memory");           \
        __builtin_amdgcn_s_barrier();            \
        asm volatile("" ::: "memory");           \
    } while (0)

#define STAGE(pbase, HSTRIDE, h, kt, region)                                           \
    do {                                                                               \
        __builtin_amdgcn_global_load_lds(                                              \
            GPTR((pbase) + (size_t)((h) * (HSTRIDE)) * D_SZ + (size_t)(kt) * 64),      \
            LPTR(smem + (region) + (h) * 16384 + wave * 1024), 16, 0, 0);              \
        __builtin_amdgcn_global_load_lds(                                              \
            GPTR((pbase) + (size_t)(128 + (h) * (HSTRIDE)) * D_SZ + (size_t)(kt) * 64),\
            LPTR(smem + (region) + (h) * 16384 + 8192 + wave * 1024), 16, 0, 0);       \
    } while (0)

#define LDA(dst, base, qm)                                                             \
    do {                                                                               \
        _Pragma("unroll") for (int mi = 0; mi < 4; ++mi) {                             \
            const int row_ = (qm) * 128 + wr * 64 + mi * 16 + fr;                      \
            dst[mi][0] = *(const bf16x8*)(smem + (base) + row_ * 128 + sw0);           \
            dst[mi][1] = *(const bf16x8*)(smem + (base) + row_ * 128 + sw1);           \
        }                                                                              \
    } while (0)

#define LDB(dst, base, qn)                                                             \
    do {                                                                               \
        _Pragma("unroll") for (int nf = 0; nf < 2; ++nf) {                             \
            const int row_ = (qn) * 128 + wc * 32 + nf * 16 + fr;                      \
            dst[nf][0] = *(const bf16x8*)(smem + (base) + row_ * 128 + sw0);           \
            dst[nf][1] = *(const bf16x8*)(smem + (base) + row_ * 128 + sw1);           \
        }                                                                              \
    } while (0)

#define MFMA_Q(qm, qn, areg, breg)                                                     \
    do {                                                                               \
        _Pragma("unroll") for (int mi = 0; mi < 4; ++mi)                               \
        _Pragma("unroll") for (int nf = 0; nf < 2; ++nf)                               \
        _Pragma("unroll") for (int ks = 0; ks < 2; ++ks)                               \
            acc[(qm) * 4 + mi][(qn) * 2 + nf] =                                        \
                __builtin_amdgcn_mfma_f32_16x16x32_bf16(                               \
                    areg[mi][ks], breg[nf][ks],                                        \
                    acc[(qm) * 4 + mi][(qn) * 2 + nf], 0, 0, 0);                       \
    } while (0)

// One K-tile, static LDS region bases. Region safety + vmcnt accounting as in
// round 2: cur regions restaged for t+2 one phase after their last ds_read;
// othB restaged for t+1 in ph1; vmcnt(6)=3 half-tiles in flight before the
// group-final barrier drains exactly tile t+1.
#define TILE(tcur, CA, CB, OB)                                                         \
    {                                                                                  \
        /* phase 1: q(0,0) */                                                          \
        LDA(a, CA, 0);                                                                 \
        LDB(b0, CB, 0);                                                                \
        if ((tcur) + 1 < NT) STAGE(pB, 32, 1, (tcur) + 1, OB);                         \
        BAR();                                                                         \
        asm volatile("s_waitcnt lgkmcnt(0)" ::: "memory");                             \
        __builtin_amdgcn_s_setprio(1);                                                 \
        MFMA_Q(0, 0, a, b0);                                                           \
        __builtin_amdgcn_s_setprio(0);                                                 \
        BAR();                                                                         \
        /* phase 2: q(0,1) */                                                          \
        LDB(b1, CB, 1);                                                                \
        if ((tcur) + 2 < NT) STAGE(pA, 64, 0, (tcur) + 2, CA);                         \
        BAR();                                                                         \
        asm volatile("s_waitcnt lgkmcnt(0)" ::: "memory");                             \
        __builtin_amdgcn_s_setprio(1);                                                 \
        MFMA_Q(0, 1, a, b1);                                                           \
        __builtin_amdgcn_s_setprio(0);                                                 \
        BAR();                                                                         \
        /* phase 3: q(1,0) */                                                          \
        LDA(a, CA, 1);                                                                 \
        if ((tcur) + 2 < NT) STAGE(pB, 32, 0, (tcur) + 2, CB);                         \
        BAR();                                                                         \
        asm volatile("s_waitcnt lgkmcnt(0)" ::: "memory");                             \
        __builtin_amdgcn_s_setprio(1);                                                 \
        MFMA_Q(1, 0, a, b0);                                                           \
        __builtin_amdgcn_s_setprio(0);                                                 \
        BAR();                                                                         \
        /* phase 4: q(1,1) */                                                          \
        if ((tcur) + 2 < NT) STAGE(pA, 64, 1, (tcur) + 2, CA);                         \
        BAR();                                                                         \
        __builtin_amdgcn_s_setprio(1);                                                 \
        MFMA_Q(1, 1, a, b1);                                                           \
        __builtin_amdgcn_s_setprio(0);                                                 \
        if ((tcur) + 2 < NT) {                                                         \
            asm volatile("s_waitcnt vmcnt(6)" ::: "memory");                           \
        } else if ((tcur) + 1 < NT) {                                                  \
            asm volatile("s_waitcnt vmcnt(0)" ::: "memory");                           \
        }                                                                              \
        BAR();                                                                         \
    }

__device__ __forceinline__ float fsig(float x) { return 1.f / (1.f + __expf(-x)); }
__device__ __forceinline__ float ftanh(float x) {
    x = fminf(fmaxf(x, -15.f), 15.f);
    float e = __expf(2.f * x);
    return (e - 1.f) / (e + 1.f);
}

__global__ __launch_bounds__(512, 2) void gemm8_k(
    const __hip_bfloat16* __restrict__ A,   // comb [8192][4096]
    const __hip_bfloat16* __restrict__ BT,  // WT   [8192][4096] (gate-interleaved rows)
    const float* __restrict__ cell,         // [8192][2048]
    const float* __restrict__ bfb, const float* __restrict__ bcb,
    const float* __restrict__ bib, const float* __restrict__ bob,
    float* __restrict__ out)                // [out | hid | cst], each [8192][2048]
{
    extern __shared__ char smem[];

    const int tid  = threadIdx.x;
    const int wave = tid >> 6;
    const int lane = tid & 63;
    const int wr = wave >> 2;   // 0..1
    const int wc = wave & 3;    // 0..3
    const int fr = lane & 15;
    const int sw0 = (((lane >> 4) + 0) ^ (fr & 7)) << 4;
    const int sw1 = (((lane >> 4) + 4) ^ (fr & 7)) << 4;

    // XCD-aware swizzle (bijective: 1024 % 8 == 0)
    const int wg = (blockIdx.x & 7) * 128 + (blockIdx.x >> 3);
    const int n0 = (wg & 31) * 256;
    const int m0 = (wg >> 5) * 256;

    const int r0   = tid >> 3;
    const int col0 = ((tid & 7) ^ (r0 & 7)) << 3;
    const __hip_bfloat16* pA = A  + (size_t)(m0 + r0) * D_SZ + col0;
    const __hip_bfloat16* pB = BT + (size_t)(n0 + ((r0 >> 5) << 6) + (r0 & 31)) * D_SZ + col0;

    f32x4 acc[8][4] = {};
    bf16x8 a[4][2], b0[2][2], b1[2][2];

    // prologue: tile0 -> buf0, tile1 A0,B0,A1 -> buf1
    STAGE(pA, 64, 0, 0, 0);
    STAGE(pB, 32, 0, 0, 32768);
    STAGE(pA, 64, 1, 0, 0);
    STAGE(pB, 32, 1, 0, 32768);
    STAGE(pA, 64, 0, 1, 65536);
    STAGE(pB, 32, 0, 1, 98304);
    STAGE(pA, 64, 1, 1, 65536);
    asm volatile("s_waitcnt vmcnt(6)" ::: "memory");
    BAR();

    for (int t = 0; t < NT; t += 2) {
        TILE(t,     0,     32768, 98304);   // even: cur=buf0, other B=buf1
        TILE(t + 1, 65536, 98304, 32768);   // odd:  cur=buf1, other B=buf0
    }

    // ---- fused LSTM epilogue. C/D: col=lane&15, row=(lane>>4)*4+j.
    // n' = n0 + wc*64 + bj*16 + ccol  ->  g = bj, h = ((n0+wc*64)>>6)*16 + ccol.
    const int crow = (lane >> 4) * 4;
    const int ccol = lane & 15;
    const int hh = (((n0 + wc * 64) >> 6) << 4) + ccol;
    const float bf_ = bfb[hh], bc_ = bcb[hh], bi_ = bib[hh], bo_ = bob[hh];
    const size_t BH = (size_t)B_SZ * H_SZ;
    float* hidp = out + BH;
    float* cstp = out + 2 * BH;
#pragma unroll
    for (int ai = 0; ai < 8; ++ai) {
#pragma unroll
        for (int j = 0; j < 4; ++j) {
            const size_t r = (size_t)(m0 + wr * 128 + ai * 16 + crow + j);
            const size_t idx = r * H_SZ + hh;
            const float gf = acc[ai][0][j] + bf_;
            const float gc = acc[ai][1][j] + bc_;
            const float gi = acc[ai][2][j] + bi_;
            const float go = acc[ai][3][j] + bo_;
            const float ft = fsig(gf);
            const float ct = ftanh(gc);
            const float it = fsig(fsig(gi));   // double sigmoid, faithful
            const float ot = fsig(go);
            const float cv = __builtin_nontemporal_load(cell + idx);
            const float cs = cv * ft + ct * it;
            __builtin_nontemporal_store(ot, out + idx);
            __builtin_nontemporal_store(cs, cstp + idx);
            __builtin_nontemporal_store(ot * ftanh(cs), hidp + idx);
        }
    }
}

// ---------------------------------------------------------------------------
extern "C" void kernel_launch(void* const* d_in, const int* in_sizes, int n_in,
                              void* d_out, int out_size, void* d_ws, size_t ws_size,
                              hipStream_t stream) {
    const float* input  = (const float*)d_in[0];
    const float* hidden = (const float*)d_in[1];
    const float* cell   = (const float*)d_in[2];
    const float* Wf     = (const float*)d_in[3];
    const float* bfb    = (const float*)d_in[4];
    const float* Wc     = (const float*)d_in[5];
    const float* bcb    = (const float*)d_in[6];
    const float* Wi     = (const float*)d_in[7];
    const float* bib    = (const float*)d_in[8];
    const float* Wo     = (const float*)d_in[9];
    const float* bob    = (const float*)d_in[10];
    float* out = (float*)d_out;

    char* ws = (char*)d_ws;
    __hip_bfloat16* comb = (__hip_bfloat16*)ws;                              // 64 MiB
    __hip_bfloat16* WT   = (__hip_bfloat16*)(ws + (size_t)B_SZ * D_SZ * 2);  // 64 MiB

    hipFuncSetAttribute(reinterpret_cast<const void*>(gemm8_k),
                        hipFuncAttributeMaxDynamicSharedMemorySize, 131072);

    prep_k<<<2048 + 32768, 256, 0, stream>>>(input, hidden, comb, Wf, Wc, Wi, Wo, WT);
    gemm8_k<<<1024, 512, 131072, stream>>>(comb, WT, cell, bfb, bcb, bib, bob, out);
}